// Round 1
// baseline (96.168 us; speedup 1.0000x reference)
//
#include <hip/hip_runtime.h>
#include <math.h>

#define EPSF 1e-6f

constexpr int B_ = 8, Q_ = 900, C1_ = 92, T_ = 1600;
constexpr int NROW = B_ * Q_;       // 7200
constexpr int PSTRIDE = 96;         // padded prob row stride (16B aligned)
constexpr int RPB = 16;             // rows per block in main kernel
constexpr int TPB = 320;            // threads per block (5 waves), 5 tiles * 320 = 1600

// ---------------- precompute: softmax probs + per-box derived ----------------
__global__ __launch_bounds__(64) void precompute_kernel(
    const float* __restrict__ logits,   // [NROW, 92]
    const float* __restrict__ pbox,     // [NROW, 4] corners
    const float* __restrict__ tbox,     // [T, 4] corners
    float* __restrict__ probs,          // [NROW, 96]
    float* __restrict__ predd,          // [NROW, 8]
    float* __restrict__ tgtd)           // [T, 8]
{
    const int bid  = blockIdx.x;
    const int lane = threadIdx.x;

    if (bid < NROW) {
        // one wave per query row: softmax over 92 classes
        const float* lrow = logits + (size_t)bid * C1_;
        float x0 = -INFINITY, x1 = -INFINITY;
        if (lane < C1_)      x0 = lrow[lane];
        if (lane + 64 < C1_) x1 = lrow[lane + 64];
        float m = fmaxf(x0, x1);
        #pragma unroll
        for (int off = 32; off; off >>= 1) m = fmaxf(m, __shfl_xor(m, off));
        float e0 = (lane < C1_)      ? __expf(x0 - m) : 0.0f;
        float e1 = (lane + 64 < C1_) ? __expf(x1 - m) : 0.0f;
        float s = e0 + e1;
        #pragma unroll
        for (int off = 32; off; off >>= 1) s += __shfl_xor(s, off);
        const float inv = 1.0f / s;
        float* prow = probs + (size_t)bid * PSTRIDE;
        if (lane < C1_)      prow[lane]      = e0 * inv;
        if (lane + 64 < C1_) prow[lane + 64] = e1 * inv;

        if (lane == 0) {
            const float bx1 = pbox[bid * 4 + 0];
            const float by1 = pbox[bid * 4 + 1];
            const float bx2 = pbox[bid * 4 + 2];
            const float by2 = pbox[bid * 4 + 3];
            const float w = bx2 - bx1, h = by2 - by1;
            float* d = predd + bid * 8;
            d[0] = bx1; d[1] = by1; d[2] = bx2; d[3] = by2;
            d[4] = w * h;
            d[5] = atanf(w / (h + EPSF));
            d[6] = bx1 + bx2;
            d[7] = by1 + by2;
        }
    } else {
        const int t = (bid - NROW) * 64 + lane;
        if (t < T_) {
            const float bx1 = tbox[t * 4 + 0];
            const float by1 = tbox[t * 4 + 1];
            const float bx2 = tbox[t * 4 + 2];
            const float by2 = tbox[t * 4 + 3];
            const float w = bx2 - bx1, h = by2 - by1;
            float* d = tgtd + t * 8;
            d[0] = bx1; d[1] = by1; d[2] = bx2; d[3] = by2;
            d[4] = w * h;
            d[5] = atanf(w / (h + EPSF));
            d[6] = bx1 + bx2;
            d[7] = by1 + by2;
        }
    }
}

// ---------------- main: pairwise cost, one target per thread ----------------
__global__ __launch_bounds__(TPB) void cost_kernel(
    const float* __restrict__ probs,   // [NROW, 96]
    const float* __restrict__ predd,   // [NROW, 8]
    const float* __restrict__ tgtd,    // [T, 8]
    const int*   __restrict__ ids,     // [T]
    float* __restrict__ out)           // [NROW, T]
{
    const int t = blockIdx.x * TPB + threadIdx.x;   // gridDim.x * TPB == T_
    // target data lives in registers for the whole block lifetime
    const float4 ta = *(const float4*)(tgtd + (size_t)t * 8);
    const float4 tb = *(const float4*)(tgtd + (size_t)t * 8 + 4);
    const int id = ids[t];
    const float tx1 = ta.x, ty1 = ta.y, tx2 = ta.z, ty2 = ta.w;
    const float area2 = tb.x, atan2t = tb.y, sx2 = tb.z, sy2 = tb.w;

    int row = blockIdx.y * RPB;
    #pragma unroll 4
    for (int r = 0; r < RPB; ++r, ++row) {
        const float* pd = predd + (size_t)row * 8;
        const float4 pa = *(const float4*)(pd);
        const float4 pb = *(const float4*)(pd + 4);
        const float px1 = pa.x, py1 = pa.y, px2 = pa.z, py2 = pa.w;
        const float area1 = pb.x, atan1t = pb.y, sx1 = pb.z, sy1 = pb.w;

        const float prob = probs[(size_t)row * PSTRIDE + id];

        // intersection / union / iou
        const float ix1 = fmaxf(px1, tx1);
        const float iy1 = fmaxf(py1, ty1);
        const float ix2 = fminf(px2, tx2);
        const float iy2 = fminf(py2, ty2);
        const float inter = fmaxf(ix2 - ix1, 0.0f) * fmaxf(iy2 - iy1, 0.0f);
        const float uni = area1 + area2 - inter;
        const float iou = inter * __builtin_amdgcn_rcpf(uni + EPSF);

        // convex diag + center distance penalty
        const float cw = fmaxf(px2, tx2) - fminf(px1, tx1);
        const float ch = fmaxf(py2, ty2) - fminf(py1, ty1);
        const float diag = cw * cw + ch * ch;
        const float dx = sx2 - sx1, dy = sy2 - sy1;
        const float cdist = dx * dx + dy * dy;
        const float dist_pen = cdist * __builtin_amdgcn_rcpf(diag + EPSF) * 0.25f;

        // aspect-ratio term
        const float dat = atan2t - atan1t;
        const float v = (4.0f / (float)(M_PI * M_PI)) * dat * dat;
        const float av = v * v * __builtin_amdgcn_rcpf(1.0f + EPSF - iou + v);

        const float ciou = iou - dist_pen - av;

        // L1 bbox cost
        const float cost_bbox = fabsf(px1 - tx1) + fabsf(py1 - ty1) +
                                fabsf(px2 - tx2) + fabsf(py2 - ty2);

        out[(size_t)row * T_ + t] = cost_bbox - prob - ciou;
    }
}

extern "C" void kernel_launch(void* const* d_in, const int* in_sizes, int n_in,
                              void* d_out, int out_size, void* d_ws, size_t ws_size,
                              hipStream_t stream) {
    const float* logits = (const float*)d_in[0];  // [8,900,92]
    const float* pbox   = (const float*)d_in[1];  // [8,900,4]
    const int*   ids    = (const int*)d_in[2];    // [1600]
    const float* tbox   = (const float*)d_in[3];  // [1600,4]
    float* out = (float*)d_out;

    float* ws    = (float*)d_ws;
    float* probs = ws;                         // NROW*96
    float* predd = probs + (size_t)NROW * PSTRIDE;  // NROW*8
    float* tgtd  = predd + (size_t)NROW * 8;        // T*8

    const int nTgtBlocks = (T_ + 63) / 64;     // 25
    precompute_kernel<<<NROW + nTgtBlocks, 64, 0, stream>>>(
        logits, pbox, tbox, probs, predd, tgtd);

    cost_kernel<<<dim3(T_ / TPB, NROW / RPB), TPB, 0, stream>>>(
        probs, predd, tgtd, ids, out);
}

// Round 2
// 94.466 us; speedup vs baseline: 1.0180x; 1.0180x over previous
//
#include <hip/hip_runtime.h>
#include <math.h>

#define EPSF 1e-6f

constexpr int B_ = 8, Q_ = 900, C1_ = 92, T_ = 1600;
constexpr int NROW = B_ * Q_;       // 7200
constexpr int PSTRIDE = 96;         // padded prob row stride (16B aligned)
constexpr int RPB = 16;             // rows per block in main kernel
constexpr int TPB = 320;            // threads per block (5 waves), 5 tiles * 320 = 1600

// ---------------- precompute: softmax probs + per-box derived ----------------
__global__ __launch_bounds__(64) void precompute_kernel(
    const float* __restrict__ logits,   // [NROW, 92]
    const float* __restrict__ pbox,     // [NROW, 4] corners
    const float* __restrict__ tbox,     // [T, 4] corners
    float* __restrict__ probs,          // [NROW, 96]
    float* __restrict__ predd,          // [NROW, 8]
    float* __restrict__ tgtd)           // [T, 8]
{
    const int bid  = blockIdx.x;
    const int lane = threadIdx.x;

    if (bid < NROW) {
        // one wave per query row: softmax over 92 classes
        const float* lrow = logits + (size_t)bid * C1_;
        float x0 = -INFINITY, x1 = -INFINITY;
        if (lane < C1_)      x0 = lrow[lane];
        if (lane + 64 < C1_) x1 = lrow[lane + 64];
        float m = fmaxf(x0, x1);
        #pragma unroll
        for (int off = 32; off; off >>= 1) m = fmaxf(m, __shfl_xor(m, off));
        float e0 = (lane < C1_)      ? __expf(x0 - m) : 0.0f;
        float e1 = (lane + 64 < C1_) ? __expf(x1 - m) : 0.0f;
        float s = e0 + e1;
        #pragma unroll
        for (int off = 32; off; off >>= 1) s += __shfl_xor(s, off);
        const float inv = 1.0f / s;
        float* prow = probs + (size_t)bid * PSTRIDE;
        if (lane < C1_)      prow[lane]      = e0 * inv;
        if (lane + 64 < C1_) prow[lane + 64] = e1 * inv;

        if (lane == 0) {
            const float bx1 = pbox[bid * 4 + 0];
            const float by1 = pbox[bid * 4 + 1];
            const float bx2 = pbox[bid * 4 + 2];
            const float by2 = pbox[bid * 4 + 3];
            const float w = bx2 - bx1, h = by2 - by1;
            float* d = predd + bid * 8;
            d[0] = bx1; d[1] = by1; d[2] = bx2; d[3] = by2;
            d[4] = w * h;
            d[5] = atanf(w / (h + EPSF));
            d[6] = bx1 + bx2;
            d[7] = by1 + by2;
        }
    } else {
        const int t = (bid - NROW) * 64 + lane;
        if (t < T_) {
            const float bx1 = tbox[t * 4 + 0];
            const float by1 = tbox[t * 4 + 1];
            const float bx2 = tbox[t * 4 + 2];
            const float by2 = tbox[t * 4 + 3];
            const float w = bx2 - bx1, h = by2 - by1;
            float* d = tgtd + t * 8;
            d[0] = bx1; d[1] = by1; d[2] = bx2; d[3] = by2;
            d[4] = w * h;
            d[5] = atanf(w / (h + EPSF));
            d[6] = bx1 + bx2;
            d[7] = by1 + by2;
        }
    }
}

// ---------------- main: pairwise cost, one target per thread ----------------
// LDS-staged: block loads 16 rows of probs (16x96, contiguous thanks to pad)
// + 16x8 predd with coalesced float4 loads; inner loop is LDS-only + store.
__global__ __launch_bounds__(TPB) void cost_kernel(
    const float* __restrict__ probs,   // [NROW, 96]
    const float* __restrict__ predd,   // [NROW, 8]
    const float* __restrict__ tgtd,    // [T, 8]
    const int*   __restrict__ ids,     // [T]
    float* __restrict__ out)           // [NROW, T]
{
    __shared__ float sprobs[RPB * PSTRIDE];   // 6144 B
    __shared__ float spredd[RPB * 8];         // 512 B

    const int tid  = threadIdx.x;
    const int t    = blockIdx.x * TPB + tid;   // gridDim.x * TPB == T_
    const int row0 = blockIdx.y * RPB;

    // ---- stage probs: 16 rows x 96 = 1536 floats = 384 float4, contiguous ----
    {
        const float4* gp4 = (const float4*)(probs + (size_t)row0 * PSTRIDE);
        float4* sp4 = (float4*)sprobs;
        sp4[tid] = gp4[tid];
        if (tid < RPB * PSTRIDE / 4 - TPB)      // 384 - 320 = 64
            sp4[tid + TPB] = gp4[tid + TPB];
        const float4* gd4 = (const float4*)(predd + (size_t)row0 * 8);
        float4* sd4 = (float4*)spredd;
        if (tid < RPB * 8 / 4)                  // 32
            sd4[tid] = gd4[tid];
    }

    // ---- target data in registers for the whole block lifetime ----
    const float4 ta = *(const float4*)(tgtd + (size_t)t * 8);
    const float4 tb = *(const float4*)(tgtd + (size_t)t * 8 + 4);
    const int id = ids[t];
    const float tx1 = ta.x, ty1 = ta.y, tx2 = ta.z, ty2 = ta.w;
    const float area2 = tb.x, atan2t = tb.y, sx2 = tb.z, sy2 = tb.w;

    __syncthreads();

    float* outp = out + (size_t)row0 * T_ + t;
    #pragma unroll 4
    for (int r = 0; r < RPB; ++r) {
        const float4 pa = *(const float4*)(spredd + r * 8);
        const float4 pb = *(const float4*)(spredd + r * 8 + 4);
        const float px1 = pa.x, py1 = pa.y, px2 = pa.z, py2 = pa.w;
        const float area1 = pb.x, atan1t = pb.y, sx1 = pb.z, sy1 = pb.w;

        const float prob = sprobs[r * PSTRIDE + id];

        // intersection / union / iou
        const float ix1 = fmaxf(px1, tx1);
        const float iy1 = fmaxf(py1, ty1);
        const float ix2 = fminf(px2, tx2);
        const float iy2 = fminf(py2, ty2);
        const float inter = fmaxf(ix2 - ix1, 0.0f) * fmaxf(iy2 - iy1, 0.0f);
        const float uni = area1 + area2 - inter;
        const float iou = inter * __builtin_amdgcn_rcpf(uni + EPSF);

        // convex diag + center distance penalty
        const float cw = fmaxf(px2, tx2) - fminf(px1, tx1);
        const float ch = fmaxf(py2, ty2) - fminf(py1, ty1);
        const float diag = cw * cw + ch * ch;
        const float dx = sx2 - sx1, dy = sy2 - sy1;
        const float cdist = dx * dx + dy * dy;
        const float dist_pen = cdist * __builtin_amdgcn_rcpf(diag + EPSF) * 0.25f;

        // aspect-ratio term
        const float dat = atan2t - atan1t;
        const float v = (4.0f / (float)(M_PI * M_PI)) * dat * dat;
        const float av = v * v * __builtin_amdgcn_rcpf(1.0f + EPSF - iou + v);

        const float ciou = iou - dist_pen - av;

        // L1 bbox cost
        const float cost_bbox = fabsf(px1 - tx1) + fabsf(py1 - ty1) +
                                fabsf(px2 - tx2) + fabsf(py2 - ty2);

        __builtin_nontemporal_store(cost_bbox - prob - ciou, outp);
        outp += T_;
    }
}

extern "C" void kernel_launch(void* const* d_in, const int* in_sizes, int n_in,
                              void* d_out, int out_size, void* d_ws, size_t ws_size,
                              hipStream_t stream) {
    const float* logits = (const float*)d_in[0];  // [8,900,92]
    const float* pbox   = (const float*)d_in[1];  // [8,900,4]
    const int*   ids    = (const int*)d_in[2];    // [1600]
    const float* tbox   = (const float*)d_in[3];  // [1600,4]
    float* out = (float*)d_out;

    float* ws    = (float*)d_ws;
    float* probs = ws;                              // NROW*96
    float* predd = probs + (size_t)NROW * PSTRIDE;  // NROW*8
    float* tgtd  = predd + (size_t)NROW * 8;        // T*8

    const int nTgtBlocks = (T_ + 63) / 64;     // 25
    precompute_kernel<<<NROW + nTgtBlocks, 64, 0, stream>>>(
        logits, pbox, tbox, probs, predd, tgtd);

    cost_kernel<<<dim3(T_ / TPB, NROW / RPB), TPB, 0, stream>>>(
        probs, predd, tgtd, ids, out);
}